// Round 3
// baseline (2741.808 us; speedup 1.0000x reference)
//
#include <hip/hip_runtime.h>
#include <math.h>

// SLIC superpixel segmentation — bit-faithful f32 reimplementation of the JAX ref
// (XLA CPU semantics). Numerics decisions, all aimed at exact label match:
//  - dot(feats, centers) replicates Eigen sgemm: sequential k=0..4 FMA chain.
//  - f_sq / c_sq: rounded squares, sequential adds, NO fma (fp contract off).
//  - d = (f_sq + c_sq) - 2*dot, three separately-rounded ops.
//  - strict-< argmin (first occurrence, == jnp.argmin).
//  - segment_sum: EXACT ascending-pixel-index sequential adds per cluster,
//    via stable counting sort (block hist -> prefix -> rank scatter).
// R3 perf changes (no arithmetic reordering):
//  - scatter writes cluster-sorted FEATURE PLANES (SoA) so update streams
//    contiguous memory instead of a dependent img gather chain (279us/dispatch).
//  - update parallelized to one thread per (cluster, channel): 4000 threads.
//  - assign packs centers as 8-float stride in LDS -> ds_read_b128+b64 per
//    cluster instead of 5x ds_read_b32 (LDS-pipe was the assign bottleneck).

#pragma clang fp contract(off)

#define BATCH 8
#define HH 224
#define WW 224
#define HWPIX (HH * WW)        // 50176
#define KSEG 100
#define NBLK (HWPIX / 256)     // 196, exact
#define NITER 10

__device__ __forceinline__ float get_ratio() {
    double S = sqrt((double)(HH * WW) / (double)KSEG);
    return (float)(10.0 / S);
}

__global__ void k_init(const float* __restrict__ img, float* __restrict__ centers) {
#pragma clang fp contract(off)
    int b = blockIdx.x;
    int k = threadIdx.x;
    if (k >= KSEG) return;
    int i = k / 10, j = k % 10;
    int y = (int)floor(((i + 0.5) * (double)HH) / 10.0);
    int x = (int)floor(((j + 0.5) * (double)WW) / 10.0);
    float ratio = get_ratio();
    int n = y * WW + x;
    const float* p = img + ((size_t)b * HWPIX + n) * 3;
    float* c = centers + (b * KSEG + k) * 5;
    c[0] = (float)y * ratio;
    c[1] = (float)x * ratio;
    c[2] = p[0];
    c[3] = p[1];
    c[4] = p[2];
}

// mode 0: write labels + per-block histogram.  mode 1: write final outputs.
__global__ void k_assign(const float* __restrict__ img, const float* __restrict__ centers,
                         int* __restrict__ labels, int* __restrict__ blockHist,
                         float* __restrict__ outLab, float* __restrict__ outMean, int mode) {
#pragma clang fp contract(off)
    __shared__ float c8[KSEG * 8];   // [c0,c1,c2,c3,c4,csq,pad,pad] per cluster
    __shared__ int hist[KSEG];
    int b = blockIdx.y, bx = blockIdx.x, tid = threadIdx.x;

    for (int i = tid; i < KSEG * 5; i += 256) {
        int k = i / 5, f = i - 5 * k;
        c8[k * 8 + f] = centers[(size_t)b * KSEG * 5 + i];
    }
    if (tid < KSEG) hist[tid] = 0;
    __syncthreads();
    if (tid < KSEG) {
        const float* ck = c8 + tid * 8;
        float s = ck[0] * ck[0];       // XLA fused mul+reduce: no fma, seq adds
        s = s + ck[1] * ck[1];
        s = s + ck[2] * ck[2];
        s = s + ck[3] * ck[3];
        s = s + ck[4] * ck[4];
        c8[tid * 8 + 5] = s;
    }
    __syncthreads();

    int n = bx * 256 + tid;                 // NBLK*256 == HWPIX exactly, no OOB
    int y = n / WW, x = n - y * WW;
    float ratio = get_ratio();
    float yf = (float)y * ratio, xf = (float)x * ratio;
    const float* p = img + ((size_t)b * HWPIX + n) * 3;
    float r = p[0], g = p[1], bl = p[2];
    float fsq = yf * yf;                    // no fma, seq adds (XLA reduce)
    fsq = fsq + xf * xf;
    fsq = fsq + r * r;
    fsq = fsq + g * g;
    fsq = fsq + bl * bl;

    float dmin = INFINITY;
    int kb = 0;
    for (int k = 0; k < KSEG; ++k) {
        float4 v0 = *reinterpret_cast<const float4*>(&c8[k * 8]);      // ds_read_b128
        float c4v = c8[k * 8 + 4];                                     // ds_read_b64
        float csqv = c8[k * 8 + 5];
        // Eigen sgemm micro-kernel: sequential FMA chain over the contracted dim
        float dot = yf * v0.x;              // == fma(yf, c0, 0)
        dot = __fmaf_rn(xf, v0.y, dot);
        dot = __fmaf_rn(r,  v0.z, dot);
        dot = __fmaf_rn(g,  v0.w, dot);
        dot = __fmaf_rn(bl, c4v, dot);
        float d = (fsq + csqv) - 2.0f * dot;    // three separately-rounded ops
        if (d < dmin) { dmin = d; kb = k; }     // strict < == first-min == jnp.argmin
    }
    labels[(size_t)b * HWPIX + n] = kb;

    if (mode == 0) {
        atomicAdd(&hist[kb], 1);
        __syncthreads();
        if (tid < KSEG) blockHist[((size_t)b * NBLK + bx) * KSEG + tid] = hist[tid];
    } else {
        outLab[(size_t)b * HWPIX + n] = (float)kb;
        float* om = outMean + ((size_t)b * HWPIX + n) * 3;
        om[0] = c8[kb * 8 + 2];
        om[1] = c8[kb * 8 + 3];
        om[2] = c8[kb * 8 + 4];
    }
}

__global__ void k_prefix(const int* __restrict__ blockHist, int* __restrict__ offsets,
                         int* __restrict__ cbase, int* __restrict__ ccount) {
    __shared__ int cnt[KSEG];
    int b = blockIdx.x, k = threadIdx.x;
    int run = 0;
    if (k < KSEG) {
        for (int blk = 0; blk < NBLK; ++blk) run += blockHist[((size_t)b * NBLK + blk) * KSEG + k];
        cnt[k] = run;
    }
    __syncthreads();
    if (k < KSEG) {
        int base = 0;
        for (int j = 0; j < k; ++j) base += cnt[j];
        int off = base;
        for (int blk = 0; blk < NBLK; ++blk) {
            size_t idx = ((size_t)b * NBLK + blk) * KSEG + k;
            int t = blockHist[idx];
            offsets[idx] = off;
            off += t;
        }
        cbase[b * KSEG + k] = base;
        ccount[b * KSEG + k] = run;
    }
}

// Stable scatter: write each pixel's 5 feature values to its sorted position,
// as 5 SoA planes per batch -> k_update streams contiguous memory.
__global__ void k_scatter(const float* __restrict__ img, const int* __restrict__ labels,
                          const int* __restrict__ offsets, float* __restrict__ sortedF) {
#pragma clang fp contract(off)
    __shared__ int lab[256];
    int b = blockIdx.y, bx = blockIdx.x, tid = threadIdx.x;
    int n = bx * 256 + tid;
    int my = labels[(size_t)b * HWPIX + n];
    lab[tid] = my;
    __syncthreads();
    int rank = 0;                            // stable rank within block
    for (int j = 0; j < tid; ++j) rank += (lab[j] == my) ? 1 : 0;
    int pos = offsets[((size_t)b * NBLK + bx) * KSEG + my] + rank;

    int y = n / WW, x = n - y * WW;
    float ratio = get_ratio();
    const float* p = img + ((size_t)b * HWPIX + n) * 3;   // coalesced (n sequential)
    float* sf = sortedF + (size_t)b * 5 * HWPIX;
    sf[0 * HWPIX + pos] = (float)y * ratio;
    sf[1 * HWPIX + pos] = (float)x * ratio;
    sf[2 * HWPIX + pos] = p[0];
    sf[3 * HWPIX + pos] = p[1];
    sf[4 * HWPIX + pos] = p[2];
}

// One thread per (cluster, channel): sequential adds in ascending pixel order
// (identical order/values to the reference scatter-add), contiguous reads.
__global__ void k_update(const float* __restrict__ sortedF, const int* __restrict__ cbase,
                         const int* __restrict__ ccount, float* __restrict__ centers) {
#pragma clang fp contract(off)
    int b = blockIdx.x, tid = threadIdx.x;
    if (tid >= KSEG * 5) return;
    int k = tid / 5, ch = tid - 5 * k;
    int base = cbase[b * KSEG + k], cnt = ccount[b * KSEG + k];
    const float* sf = sortedF + ((size_t)b * 5 + ch) * HWPIX + base;
    float s = 0.f;
    for (int i = 0; i < cnt; ++i) s = s + sf[i];   // ascending pixel order
    if (cnt > 0) {                                 // where(counts>0, sums/counts, old)
        centers[(b * KSEG + k) * 5 + ch] = s / (float)cnt;
    }
}

extern "C" void kernel_launch(void* const* d_in, const int* in_sizes, int n_in,
                              void* d_out, int out_size, void* d_ws, size_t ws_size,
                              hipStream_t stream) {
    const float* img = (const float*)d_in[0];
    float* outLab = (float*)d_out;                         // [8,224,224] labels as f32
    float* outMean = outLab + (size_t)BATCH * HWPIX;       // [8,224,224,3]

    char* ws = (char*)d_ws;
    float* centers = (float*)ws;  ws += (size_t)BATCH * KSEG * 5 * sizeof(float);
    int* labels    = (int*)ws;    ws += (size_t)BATCH * HWPIX * sizeof(int);
    int* blockHist = (int*)ws;    ws += (size_t)BATCH * NBLK * KSEG * sizeof(int);
    int* offsets   = (int*)ws;    ws += (size_t)BATCH * NBLK * KSEG * sizeof(int);
    float* sortedF = (float*)ws;  ws += (size_t)BATCH * 5 * HWPIX * sizeof(float);
    int* cbase     = (int*)ws;    ws += (size_t)BATCH * KSEG * sizeof(int);
    int* ccount    = (int*)ws;    ws += (size_t)BATCH * KSEG * sizeof(int);

    k_init<<<dim3(BATCH), 128, 0, stream>>>(img, centers);
    for (int it = 0; it < NITER; ++it) {
        k_assign<<<dim3(NBLK, BATCH), 256, 0, stream>>>(img, centers, labels, blockHist,
                                                        outLab, outMean, 0);
        k_prefix<<<dim3(BATCH), 128, 0, stream>>>(blockHist, offsets, cbase, ccount);
        k_scatter<<<dim3(NBLK, BATCH), 256, 0, stream>>>(img, labels, offsets, sortedF);
        k_update<<<dim3(BATCH), 512, 0, stream>>>(sortedF, cbase, ccount, centers);
    }
    k_assign<<<dim3(NBLK, BATCH), 256, 0, stream>>>(img, centers, labels, blockHist,
                                                    outLab, outMean, 1);
}

// Round 4
// 729.811 us; speedup vs baseline: 3.7569x; 3.7569x over previous
//
#include <hip/hip_runtime.h>
#include <math.h>

// SLIC superpixel segmentation — bit-faithful f32 reimplementation of the JAX ref
// (XLA CPU semantics). Numerics decisions, all aimed at exact label match:
//  - dot(feats, centers) replicates Eigen sgemm: sequential k=0..4 FMA chain.
//  - f_sq / c_sq: rounded squares, sequential adds, NO fma (fp contract off).
//  - d = (f_sq + c_sq) - 2*dot, three separately-rounded ops.
//  - strict-< argmin (first occurrence, == jnp.argmin).
//  - segment_sum: EXACT ascending-pixel-index sequential adds per cluster,
//    via stable counting sort (block hist -> prefix -> rank scatter).
// R4 perf change (no arithmetic reordering):
//  - k_update: one workgroup per (batch,cluster); 256 threads stage the
//    cluster's sorted features into LDS with LANE-coalesced loads (R3's
//    per-thread-contiguous reads were uncoalesced across lanes -> 225us
//    latency-bound); then 5 lanes run the exact serial add chains from LDS.

#pragma clang fp contract(off)

#define BATCH 8
#define HH 224
#define WW 224
#define HWPIX (HH * WW)        // 50176
#define KSEG 100
#define NBLK (HWPIX / 256)     // 196, exact
#define NITER 10
#define UCHUNK 2048            // per-channel LDS chunk (5*(2048+1)*4B = 40KB)

__device__ __forceinline__ float get_ratio() {
    double S = sqrt((double)(HH * WW) / (double)KSEG);
    return (float)(10.0 / S);
}

__global__ void k_init(const float* __restrict__ img, float* __restrict__ centers) {
#pragma clang fp contract(off)
    int b = blockIdx.x;
    int k = threadIdx.x;
    if (k >= KSEG) return;
    int i = k / 10, j = k % 10;
    int y = (int)floor(((i + 0.5) * (double)HH) / 10.0);
    int x = (int)floor(((j + 0.5) * (double)WW) / 10.0);
    float ratio = get_ratio();
    int n = y * WW + x;
    const float* p = img + ((size_t)b * HWPIX + n) * 3;
    float* c = centers + (b * KSEG + k) * 5;
    c[0] = (float)y * ratio;
    c[1] = (float)x * ratio;
    c[2] = p[0];
    c[3] = p[1];
    c[4] = p[2];
}

// mode 0: write labels + per-block histogram.  mode 1: write final outputs.
__global__ void k_assign(const float* __restrict__ img, const float* __restrict__ centers,
                         int* __restrict__ labels, int* __restrict__ blockHist,
                         float* __restrict__ outLab, float* __restrict__ outMean, int mode) {
#pragma clang fp contract(off)
    __shared__ float c8[KSEG * 8];   // [c0,c1,c2,c3,c4,csq,pad,pad] per cluster
    __shared__ int hist[KSEG];
    int b = blockIdx.y, bx = blockIdx.x, tid = threadIdx.x;

    for (int i = tid; i < KSEG * 5; i += 256) {
        int k = i / 5, f = i - 5 * k;
        c8[k * 8 + f] = centers[(size_t)b * KSEG * 5 + i];
    }
    if (tid < KSEG) hist[tid] = 0;
    __syncthreads();
    if (tid < KSEG) {
        const float* ck = c8 + tid * 8;
        float s = ck[0] * ck[0];       // XLA fused mul+reduce: no fma, seq adds
        s = s + ck[1] * ck[1];
        s = s + ck[2] * ck[2];
        s = s + ck[3] * ck[3];
        s = s + ck[4] * ck[4];
        c8[tid * 8 + 5] = s;
    }
    __syncthreads();

    int n = bx * 256 + tid;                 // NBLK*256 == HWPIX exactly, no OOB
    int y = n / WW, x = n - y * WW;
    float ratio = get_ratio();
    float yf = (float)y * ratio, xf = (float)x * ratio;
    const float* p = img + ((size_t)b * HWPIX + n) * 3;
    float r = p[0], g = p[1], bl = p[2];
    float fsq = yf * yf;                    // no fma, seq adds (XLA reduce)
    fsq = fsq + xf * xf;
    fsq = fsq + r * r;
    fsq = fsq + g * g;
    fsq = fsq + bl * bl;

    float dmin = INFINITY;
    int kb = 0;
    for (int k = 0; k < KSEG; ++k) {
        float4 v0 = *reinterpret_cast<const float4*>(&c8[k * 8]);      // ds_read_b128
        float c4v = c8[k * 8 + 4];
        float csqv = c8[k * 8 + 5];
        // Eigen sgemm micro-kernel: sequential FMA chain over the contracted dim
        float dot = yf * v0.x;              // == fma(yf, c0, 0)
        dot = __fmaf_rn(xf, v0.y, dot);
        dot = __fmaf_rn(r,  v0.z, dot);
        dot = __fmaf_rn(g,  v0.w, dot);
        dot = __fmaf_rn(bl, c4v, dot);
        float d = (fsq + csqv) - 2.0f * dot;    // three separately-rounded ops
        if (d < dmin) { dmin = d; kb = k; }     // strict < == first-min == jnp.argmin
    }
    labels[(size_t)b * HWPIX + n] = kb;

    if (mode == 0) {
        atomicAdd(&hist[kb], 1);
        __syncthreads();
        if (tid < KSEG) blockHist[((size_t)b * NBLK + bx) * KSEG + tid] = hist[tid];
    } else {
        outLab[(size_t)b * HWPIX + n] = (float)kb;
        float* om = outMean + ((size_t)b * HWPIX + n) * 3;
        om[0] = c8[kb * 8 + 2];
        om[1] = c8[kb * 8 + 3];
        om[2] = c8[kb * 8 + 4];
    }
}

__global__ void k_prefix(const int* __restrict__ blockHist, int* __restrict__ offsets,
                         int* __restrict__ cbase, int* __restrict__ ccount) {
    __shared__ int cnt[KSEG];
    int b = blockIdx.x, k = threadIdx.x;
    int run = 0;
    if (k < KSEG) {
        for (int blk = 0; blk < NBLK; ++blk) run += blockHist[((size_t)b * NBLK + blk) * KSEG + k];
        cnt[k] = run;
    }
    __syncthreads();
    if (k < KSEG) {
        int base = 0;
        for (int j = 0; j < k; ++j) base += cnt[j];
        int off = base;
        for (int blk = 0; blk < NBLK; ++blk) {
            size_t idx = ((size_t)b * NBLK + blk) * KSEG + k;
            int t = blockHist[idx];
            offsets[idx] = off;
            off += t;
        }
        cbase[b * KSEG + k] = base;
        ccount[b * KSEG + k] = run;
    }
}

// Stable scatter: write each pixel's 5 feature values to its sorted position,
// as 5 SoA planes per batch -> k_update streams contiguous memory.
__global__ void k_scatter(const float* __restrict__ img, const int* __restrict__ labels,
                          const int* __restrict__ offsets, float* __restrict__ sortedF) {
#pragma clang fp contract(off)
    __shared__ int lab[256];
    int b = blockIdx.y, bx = blockIdx.x, tid = threadIdx.x;
    int n = bx * 256 + tid;
    int my = labels[(size_t)b * HWPIX + n];
    lab[tid] = my;
    __syncthreads();
    int rank = 0;                            // stable rank within block
    for (int j = 0; j < tid; ++j) rank += (lab[j] == my) ? 1 : 0;
    int pos = offsets[((size_t)b * NBLK + bx) * KSEG + my] + rank;

    int y = n / WW, x = n - y * WW;
    float ratio = get_ratio();
    const float* p = img + ((size_t)b * HWPIX + n) * 3;   // coalesced (n sequential)
    float* sf = sortedF + (size_t)b * 5 * HWPIX;
    sf[0 * HWPIX + pos] = (float)y * ratio;
    sf[1 * HWPIX + pos] = (float)x * ratio;
    sf[2 * HWPIX + pos] = p[0];
    sf[3 * HWPIX + pos] = p[1];
    sf[4 * HWPIX + pos] = p[2];
}

// One workgroup per (batch,cluster). 256 threads stage 5 x cnt sorted values
// into LDS (lane-coalesced), then 5 lanes do the EXACT ascending serial sums.
__global__ void k_update(const float* __restrict__ sortedF, const int* __restrict__ cbase,
                         const int* __restrict__ ccount, float* __restrict__ centers) {
#pragma clang fp contract(off)
    __shared__ float buf[5][UCHUNK + 1];     // +1: rows land in different banks
    int k = blockIdx.x, b = blockIdx.y, tid = threadIdx.x;
    int base = cbase[b * KSEG + k], cnt = ccount[b * KSEG + k];
    const float* sf0 = sortedF + (size_t)b * 5 * HWPIX + base;
    float acc = 0.f;
    for (int c0 = 0; c0 < cnt; c0 += UCHUNK) {
        int m = min(UCHUNK, cnt - c0);
        for (int ch = 0; ch < 5; ++ch) {
            const float* src = sf0 + (size_t)ch * HWPIX + c0;
            for (int i = tid; i < m; i += 256) buf[ch][i] = src[i];   // coalesced
        }
        __syncthreads();
        if (tid < 5) {
            float a = acc;
            const float* bp = buf[tid];
            for (int i = 0; i < m; ++i) a = a + bp[i];   // exact ascending chain
            acc = a;
        }
        __syncthreads();
    }
    if (tid < 5 && cnt > 0) {                // where(counts>0, sums/counts, old)
        centers[(b * KSEG + k) * 5 + tid] = acc / (float)cnt;
    }
}

extern "C" void kernel_launch(void* const* d_in, const int* in_sizes, int n_in,
                              void* d_out, int out_size, void* d_ws, size_t ws_size,
                              hipStream_t stream) {
    const float* img = (const float*)d_in[0];
    float* outLab = (float*)d_out;                         // [8,224,224] labels as f32
    float* outMean = outLab + (size_t)BATCH * HWPIX;       // [8,224,224,3]

    char* ws = (char*)d_ws;
    float* centers = (float*)ws;  ws += (size_t)BATCH * KSEG * 5 * sizeof(float);
    int* labels    = (int*)ws;    ws += (size_t)BATCH * HWPIX * sizeof(int);
    int* blockHist = (int*)ws;    ws += (size_t)BATCH * NBLK * KSEG * sizeof(int);
    int* offsets   = (int*)ws;    ws += (size_t)BATCH * NBLK * KSEG * sizeof(int);
    float* sortedF = (float*)ws;  ws += (size_t)BATCH * 5 * HWPIX * sizeof(float);
    int* cbase     = (int*)ws;    ws += (size_t)BATCH * KSEG * sizeof(int);
    int* ccount    = (int*)ws;    ws += (size_t)BATCH * KSEG * sizeof(int);

    k_init<<<dim3(BATCH), 128, 0, stream>>>(img, centers);
    for (int it = 0; it < NITER; ++it) {
        k_assign<<<dim3(NBLK, BATCH), 256, 0, stream>>>(img, centers, labels, blockHist,
                                                        outLab, outMean, 0);
        k_prefix<<<dim3(BATCH), 128, 0, stream>>>(blockHist, offsets, cbase, ccount);
        k_scatter<<<dim3(NBLK, BATCH), 256, 0, stream>>>(img, labels, offsets, sortedF);
        k_update<<<dim3(KSEG, BATCH), 256, 0, stream>>>(sortedF, cbase, ccount, centers);
    }
    k_assign<<<dim3(NBLK, BATCH), 256, 0, stream>>>(img, centers, labels, blockHist,
                                                    outLab, outMean, 1);
}